// Round 6
// baseline (315.836 us; speedup 1.0000x reference)
//
#include <hip/hip_runtime.h>
#include <hip/hip_bf16.h>
#include <stdint.h>

typedef __bf16 bf16;
typedef __attribute__((ext_vector_type(8))) __bf16 bf16x8;
typedef __attribute__((ext_vector_type(4))) float f32x4;

#define KREAL 784
#define NTILES 25            // 25 k-tiles of 32
#define TROW   40            // row length in elements within a k-tile (32 + 8 pad)
#define TILE_ELEMS (256 * TROW)   // 10240 elements = 20 KB per k-tile

#define GLOBAL_AS __attribute__((address_space(1)))
#define LDS_AS    __attribute__((address_space(3)))

// ---------------------------------------------------------------------------
// Prep: fold 3x3 VALID cross-correlation into w1, emit k-tiled, row-padded.
// ---------------------------------------------------------------------------
__global__ __launch_bounds__(256) void prep_w1tt(const float* __restrict__ w_conv,
                                                 const float* __restrict__ w1,
                                                 bf16* __restrict__ W) {
    const int tile = blockIdx.x / TROW;
    const int kk   = blockIdx.x % TROW;
    const int n    = threadIdx.x;
    const int k    = tile * 32 + kk;
    float s = 0.0f;
    if (kk < 32 && k < KREAL) {
        const int r = k / 28, c = k % 28;
        #pragma unroll
        for (int di = 0; di < 3; ++di) {
            const int i = r - di;
            if (i < 0 || i >= 26) continue;
            #pragma unroll
            for (int dj = 0; dj < 3; ++dj) {
                const int j = c - dj;
                if (j < 0 || j >= 26) continue;
                s += w_conv[di * 3 + dj] * w1[(i * 26 + j) * 256 + n];
            }
        }
    }
    W[(size_t)tile * TILE_ELEMS + n * TROW + kk] = (bf16)s;
}

// DPP cross-lane add (VALU pipe, no DS ops). 0xB1=xor1, 0x4E=xor2,
// 0x124=row_ror:4, 0x128=row_ror:8 (ring-sum of uniform quad-sums).
template <int CTRL>
__device__ __forceinline__ float dpp_add(float s) {
    int v = __builtin_amdgcn_update_dpp(0, __float_as_int(s), CTRL, 0xf, 0xf, false);
    return s + __int_as_float(v);
}

// ---------------------------------------------------------------------------
// Fused: out = relu(x @ W1' + b1) @ w2 + b2
// M=128/block, N=256, BK=32.  R5 structure + DEPTH-2 A PREFETCH:
//   iter it:  [VMEM issue order matters for the counted barrier]
//     1. DMA(it+1) -> buf[cur^1]            (5 ops, oldest)
//     2. A(it+2) float loads -> set[it&1]   (4 ops, youngest)
//     3. MFMAs on buf[cur] with a0/a1 (cvt'd from A(it+1) last iter? no —
//        cvt'd at end of LAST iter from set[(it)&1]; see step 4)
//     4. cvt A(it+1) from set[(it+1)&1]     (implicit wait: loads are a full
//        iter old -> no stall; drains nothing younger)
//     5. s_waitcnt vmcnt(4) + s_barrier     (drains DMA(it+1); the 4 A(it+2)
//        loads RIDE ACROSS the barrier -> ~2-iter latency window vs ~900cyc
//        HBM latency; __syncthreads' vmcnt(0) would kill this)
// Two float4 sets indexed by tile parity; loop explicitly double-stepped so
// all set indices are compile-time (runtime-indexed regs spill, rule #20).
// Epilogue: all-DPP 256->10 reduction (R5, measured −6 µs).
// ---------------------------------------------------------------------------
__global__ __launch_bounds__(256, 2) void fused_mlp(
    const float* __restrict__ x,    // (65536, 784)
    const bf16*  __restrict__ W,    // k-tiled padded W1' (25*10240 bf16)
    const float* __restrict__ b1,   // (256)
    const float* __restrict__ w2,   // (256, 10)
    const float* __restrict__ b2,   // (10)
    float* __restrict__ out)        // (65536, 10)
{
    __shared__ bf16  Bs[2][TILE_ELEMS];  // 2 x 20 KB
    __shared__ float w2s[256][10];       // 10 KB
    __shared__ float b1s[256];
    __shared__ float b2s[10];

    const int t    = threadIdx.x;
    const int wave = t >> 6;
    const int lane = t & 63;
    const int c    = lane & 15;   // MFMA col / A-row within 16-tile
    const int q    = lane >> 4;   // MFMA quad (k-chunk selector)

    const int row0 = blockIdx.x * 128;

    // epilogue constants: each ds_write consumes its load (self-draining vmem);
    // published by the prologue barrier's lgkmcnt(0).
    for (int i = t; i < 2560; i += 256) ((float*)w2s)[i] = w2[i];
    b1s[t] = b1[t];
    if (t < 10) b2s[t] = b2[t];

    // A: lane (c,q) owns rows (wave*32 + c) and (+16), k-chunk q*8..q*8+7
    const float* arow0 = x + (size_t)(row0 + wave * 32 + c) * KREAL + q * 8;
    const float* arow1 = arow0 + (size_t)16 * KREAL;
    // B DMA: wave w, instr j stages elements [(w*5+j)*512, +512) of the tile
    const bf16* bsrc = W + (size_t)(wave * 5) * 512 + lane * 8;

    f32x4 acc[2][16];
    #pragma unroll
    for (int mt = 0; mt < 2; ++mt)
        #pragma unroll
        for (int nt = 0; nt < 16; ++nt)
            acc[mt][nt] = (f32x4){0.f, 0.f, 0.f, 0.f};

    // float sets: E = even tiles, O = odd tiles. [0..3] = {r0lo, r0hi, r1lo, r1hi}
    float4 E0, E1, E2, E3, O0, O1, O2, O3;
    bf16x8 a0, a1;

    // ---- prologue: DMA(0) [oldest], A(0)->E, A(1)->O [youngest], cvt A(0) --
    #pragma unroll
    for (int j = 0; j < 5; ++j) {
        __builtin_amdgcn_global_load_lds(
            (const GLOBAL_AS void*)(bsrc + j * 512),
            (LDS_AS void*)((char*)&Bs[0][0] + (wave * 5 + j) * 1024), 16, 0, 0);
    }
    E0 = *(const float4*)arow0;        E1 = *(const float4*)(arow0 + 4);
    E2 = *(const float4*)arow1;        E3 = *(const float4*)(arow1 + 4);
    O0 = *(const float4*)(arow0 + 32); O1 = *(const float4*)(arow0 + 36);
    O2 = *(const float4*)(arow1 + 32); O3 = *(const float4*)(arow1 + 36);
    // cvt A(0): implicit vmcnt drains DMA(0)+A(0); A(1) stays in flight
    a0[0] = (bf16)E0.x; a0[1] = (bf16)E0.y; a0[2] = (bf16)E0.z; a0[3] = (bf16)E0.w;
    a0[4] = (bf16)E1.x; a0[5] = (bf16)E1.y; a0[6] = (bf16)E1.z; a0[7] = (bf16)E1.w;
    a1[0] = (bf16)E2.x; a1[1] = (bf16)E2.y; a1[2] = (bf16)E2.z; a1[3] = (bf16)E2.w;
    a1[4] = (bf16)E3.x; a1[5] = (bf16)E3.y; a1[6] = (bf16)E3.z; a1[7] = (bf16)E3.w;
    asm volatile("s_waitcnt vmcnt(4) lgkmcnt(0)" ::: "memory");
    __builtin_amdgcn_sched_barrier(0);
    __builtin_amdgcn_s_barrier();
    __builtin_amdgcn_sched_barrier(0);

    // KSTEP(IT, CUR, P*, Q*): P = set holding A(IT+1) floats (cvt here),
    //                         Q = set receiving A(IT+2) loads.
#define KSTEP(IT, CUR, P0, P1, P2, P3, Q0, Q1, Q2, Q3)                         \
    do {                                                                       \
        const int  it_    = (IT);                                              \
        const bool more_  = (it_ + 1) < NTILES;                                \
        const bool more2_ = (it_ + 2) < NTILES;                                \
        if (more_) {            /* 1. DMA(it+1) — oldest vmem this iter */     \
            const bf16* bs_ = bsrc + (size_t)(it_ + 1) * TILE_ELEMS;           \
            char* bd_ = (char*)&Bs[(CUR) ^ 1][0] + wave * 5 * 1024;            \
            _Pragma("unroll")                                                  \
            for (int j = 0; j < 5; ++j) {                                      \
                __builtin_amdgcn_global_load_lds(                              \
                    (const GLOBAL_AS void*)(bs_ + j * 512),                    \
                    (LDS_AS void*)(bd_ + j * 1024), 16, 0, 0);                 \
            }                                                                  \
        }                                                                      \
        if (more2_) {           /* 2. A(it+2) loads — youngest */              \
            const int kn_   = (it_ + 2) * 32;                                  \
            const int koff_ = (kn_ + q * 8 < KREAL) ? kn_ : 0;                 \
            Q0 = *(const float4*)(arow0 + koff_);                              \
            Q1 = *(const float4*)(arow0 + koff_ + 4);                          \
            Q2 = *(const float4*)(arow1 + koff_);                              \
            Q3 = *(const float4*)(arow1 + koff_ + 4);                          \
        }                                                                      \
        {                       /* 3. MFMAs on buf[CUR] */                     \
            const bf16* bb_ = &Bs[(CUR)][0] + c * TROW + q * 8;                \
            _Pragma("unroll")                                                  \
            for (int nt = 0; nt < 16; ++nt) {                                  \
                bf16x8 b_ = *(const bf16x8*)(bb_ + nt * 16 * TROW);            \
                acc[0][nt] = __builtin_amdgcn_mfma_f32_16x16x32_bf16(          \
                    a0, b_, acc[0][nt], 0, 0, 0);                              \
                acc[1][nt] = __builtin_amdgcn_mfma_f32_16x16x32_bf16(          \
                    a1, b_, acc[1][nt], 0, 0, 0);                              \
            }                                                                  \
        }                                                                      \
        if (more_) {            /* 4. cvt A(it+1) (loads are 1 iter old) */    \
            const float okm_ = ((it_ + 1) * 32 + q * 8 < KREAL) ? 1.f : 0.f;   \
            a0[0] = (bf16)(P0.x * okm_); a0[1] = (bf16)(P0.y * okm_);          \
            a0[2] = (bf16)(P0.z * okm_); a0[3] = (bf16)(P0.w * okm_);          \
            a0[4] = (bf16)(P1.x * okm_); a0[5] = (bf16)(P1.y * okm_);          \
            a0[6] = (bf16)(P1.z * okm_); a0[7] = (bf16)(P1.w * okm_);          \
            a1[0] = (bf16)(P2.x * okm_); a1[1] = (bf16)(P2.y * okm_);          \
            a1[2] = (bf16)(P2.z * okm_); a1[3] = (bf16)(P2.w * okm_);          \
            a1[4] = (bf16)(P3.x * okm_); a1[5] = (bf16)(P3.y * okm_);          \
            a1[6] = (bf16)(P3.z * okm_); a1[7] = (bf16)(P3.w * okm_);          \
        }                                                                      \
        if (more_) {            /* 5. counted barrier: A(it+2) rides */        \
            if (more2_) asm volatile("s_waitcnt vmcnt(4)" ::: "memory");       \
            else        asm volatile("s_waitcnt vmcnt(0)" ::: "memory");       \
            __builtin_amdgcn_sched_barrier(0);                                 \
            __builtin_amdgcn_s_barrier();                                      \
            __builtin_amdgcn_sched_barrier(0);                                 \
        }                                                                      \
    } while (0)

    #pragma unroll 1
    for (int base = 0; base < NTILES - 1; base += 2) {
        KSTEP(base,     0, O0, O1, O2, O3, E0, E1, E2, E3); // cvt odd, load even
        KSTEP(base + 1, 1, E0, E1, E2, E3, O0, O1, O2, O3); // cvt even, load odd
    }
    KSTEP(NTILES - 1, 0, O0, O1, O2, O3, E0, E1, E2, E3);   // it=24: MFMA only
#undef KSTEP

    // ---- epilogue: h = relu(acc + b1); out = h @ w2 + b2 ----
    // C/D layout: col = lane&15 (= n within tile), row = q*4 + reg
    float bl[16];
    #pragma unroll
    for (int nt = 0; nt < 16; ++nt) bl[nt] = b1s[nt * 16 + c];

    #pragma unroll
    for (int mt = 0; mt < 2; ++mt)
        #pragma unroll
        for (int nt = 0; nt < 16; ++nt)
            #pragma unroll
            for (int r = 0; r < 4; ++r) {
                float v = acc[mt][nt][r] + bl[nt];
                acc[mt][nt][r] = v > 0.f ? v : 0.f;
            }

    #pragma unroll 1
    for (int j = 0; j < 10; ++j) {
        float wj[16];
        #pragma unroll
        for (int nt = 0; nt < 16; ++nt) wj[nt] = w2s[nt * 16 + c][j];
        const float b2j = b2s[j];
        #pragma unroll
        for (int mt = 0; mt < 2; ++mt)
            #pragma unroll
            for (int r = 0; r < 4; ++r) {
                float s = 0.f;
                #pragma unroll
                for (int nt = 0; nt < 16; ++nt) s += acc[mt][nt][r] * wj[nt];
                // 16-lane sum, all DPP (VALU pipe, zero DS ops):
                s = dpp_add<0xB1>(s);    // lane ^ 1
                s = dpp_add<0x4E>(s);    // lane ^ 2
                s = dpp_add<0x124>(s);   // row_ror:4 (quad-sums uniform)
                s = dpp_add<0x128>(s);   // row_ror:8
                if (c == j) {
                    const int row = row0 + wave * 32 + mt * 16 + q * 4 + r;
                    out[(size_t)row * 10 + j] = s + b2j;
                }
            }
    }
}

extern "C" void kernel_launch(void* const* d_in, const int* in_sizes, int n_in,
                              void* d_out, int out_size, void* d_ws, size_t ws_size,
                              hipStream_t stream) {
    const float* x  = (const float*)d_in[0];
    const float* wc = (const float*)d_in[1];
    const float* w1 = (const float*)d_in[2];
    const float* b1 = (const float*)d_in[3];
    const float* w2 = (const float*)d_in[4];
    const float* b2 = (const float*)d_in[5];
    float* out = (float*)d_out;
    bf16* W = (bf16*)d_ws;  // 25 * 10240 * 2 B = 500 KB scratch

    prep_w1tt<<<dim3(NTILES * TROW), dim3(256), 0, stream>>>(wc, w1, W);
    fused_mlp<<<dim3(65536 / 128), dim3(256), 0, stream>>>(x, W, b1, w2, b2, out);
}

// Round 7
// 315.815 us; speedup vs baseline: 1.0001x; 1.0001x over previous
//
#include <hip/hip_runtime.h>
#include <hip/hip_bf16.h>
#include <stdint.h>

typedef __bf16 bf16;
typedef __attribute__((ext_vector_type(8))) __bf16 bf16x8;
typedef __attribute__((ext_vector_type(4))) float f32x4;

#define KREAL 784
#define NTILES 25            // 25 k-tiles of 32
#define TROW   40            // row length in elements within a k-tile (32 + 8 pad)
#define TILE_ELEMS (256 * TROW)   // 10240 elements = 20 KB per k-tile

#define GLOBAL_AS __attribute__((address_space(1)))
#define LDS_AS    __attribute__((address_space(3)))

// ---------------------------------------------------------------------------
// Prep: fold 3x3 VALID cross-correlation into w1, emit k-tiled, row-padded.
// ---------------------------------------------------------------------------
__global__ __launch_bounds__(256) void prep_w1tt(const float* __restrict__ w_conv,
                                                 const float* __restrict__ w1,
                                                 bf16* __restrict__ W) {
    const int tile = blockIdx.x / TROW;
    const int kk   = blockIdx.x % TROW;
    const int n    = threadIdx.x;
    const int k    = tile * 32 + kk;
    float s = 0.0f;
    if (kk < 32 && k < KREAL) {
        const int r = k / 28, c = k % 28;
        #pragma unroll
        for (int di = 0; di < 3; ++di) {
            const int i = r - di;
            if (i < 0 || i >= 26) continue;
            #pragma unroll
            for (int dj = 0; dj < 3; ++dj) {
                const int j = c - dj;
                if (j < 0 || j >= 26) continue;
                s += w_conv[di * 3 + dj] * w1[(i * 26 + j) * 256 + n];
            }
        }
    }
    W[(size_t)tile * TILE_ELEMS + n * TROW + kk] = (bf16)s;
}

// DPP cross-lane add (VALU pipe, no DS ops). 0xB1=xor1, 0x4E=xor2,
// 0x124=row_ror:4, 0x128=row_ror:8 (ring-sum of uniform quad-sums).
template <int CTRL>
__device__ __forceinline__ float dpp_add(float s) {
    int v = __builtin_amdgcn_update_dpp(0, __float_as_int(s), CTRL, 0xf, 0xf, false);
    return s + __int_as_float(v);
}

__device__ __forceinline__ bf16x8 cvt8(float4 lo, float4 hi) {
    bf16x8 r;
    r[0] = (bf16)lo.x; r[1] = (bf16)lo.y; r[2] = (bf16)lo.z; r[3] = (bf16)lo.w;
    r[4] = (bf16)hi.x; r[5] = (bf16)hi.y; r[6] = (bf16)hi.z; r[7] = (bf16)hi.w;
    return r;
}

// ---------------------------------------------------------------------------
// Fused: out = relu(x @ W1' + b1) @ w2 + b2
// M=128/block, N=256, BK=32 — R5 loop structure (best measured), with the
// WAVE MAPPING changed from 32rows x 256cols to 64rows x 128cols:
//   per-wave ds_read_b128 per iter: 16 -> 8 (each B-frag feeds 4 MFMAs);
//   per-CU LDS read volume halves (128 -> 64 KB/iter) — the quantity R3
//   showed perf tracks. MFMA count unchanged (4mt x 8nt = 32/iter/wave).
//   A: wave-pairs (2p,2p+1) load IDENTICAL A addresses -> L1 serves the
//   duplicate; HBM FETCH unchanged.
// Epilogue: per-lane keep[mt][r] (lane c keeps the j==c sum after the DPP
// ring-reduction), odd col-half waves publish 2.5 KB partials in the dead
// Bs buffer, even waves combine + store. All-DPP reduction kept (R5 win).
// ---------------------------------------------------------------------------
__global__ __launch_bounds__(256, 2) void fused_mlp(
    const float* __restrict__ x,    // (65536, 784)
    const bf16*  __restrict__ W,    // k-tiled padded W1' (25*10240 bf16)
    const float* __restrict__ b1,   // (256)
    const float* __restrict__ w2,   // (256, 10)
    const float* __restrict__ b2,   // (10)
    float* __restrict__ out)        // (65536, 10)
{
    __shared__ bf16  Bs[2][TILE_ELEMS];  // 2 x 20 KB
    __shared__ float w2s[256][10];       // 10 KB
    __shared__ float b1s[256];
    __shared__ float b2s[10];

    const int t    = threadIdx.x;
    const int wave = t >> 6;
    const int lane = t & 63;
    const int c    = lane & 15;   // MFMA col / A-row within 16-tile
    const int q    = lane >> 4;   // MFMA quad (k-chunk selector)
    const int pair = wave >> 1;   // row half: rows pair*64 .. +63
    const int nh   = wave & 1;    // col half: h-cols nh*128 .. +127

    const int row0 = blockIdx.x * 128;

    // one-time stage of epilogue constants (pre-loop barrier publishes them)
    for (int i = t; i < 2560; i += 256) ((float*)w2s)[i] = w2[i];
    b1s[t] = b1[t];
    if (t < 10) b2s[t] = b2[t];

    // A: lane (c,q), m-tile mt -> row row0 + pair*64 + mt*16 + c, k-chunk q*8
    const float* ar = x + (size_t)(row0 + pair * 64 + c) * KREAL + q * 8;
    // B DMA: wave w, instr j stages elements [(w*5+j)*512, +512) of the tile
    const bf16* bsrc = W + (size_t)(wave * 5) * 512 + lane * 8;

    f32x4 acc[4][8];
    #pragma unroll
    for (int mt = 0; mt < 4; ++mt)
        #pragma unroll
        for (int nt = 0; nt < 8; ++nt)
            acc[mt][nt] = (f32x4){0.f, 0.f, 0.f, 0.f};

    // ---- prologue: DMA tile 0, load+cvt A(0) ----
    #pragma unroll
    for (int j = 0; j < 5; ++j) {
        __builtin_amdgcn_global_load_lds(
            (const GLOBAL_AS void*)(bsrc + j * 512),
            (LDS_AS void*)((char*)&Bs[0][0] + (wave * 5 + j) * 1024), 16, 0, 0);
    }
    float4 fa[4], fb[4];
    #pragma unroll
    for (int mt = 0; mt < 4; ++mt) {
        const float* p = ar + (size_t)(mt * 16) * KREAL;
        fa[mt] = *(const float4*)p;
        fb[mt] = *(const float4*)(p + 4);
    }
    bf16x8 a[4];
    #pragma unroll
    for (int mt = 0; mt < 4; ++mt) a[mt] = cvt8(fa[mt], fb[mt]);
    __syncthreads();   // tile 0 resident; w2s/b1s/b2s published

    #pragma unroll 1
    for (int it = 0; it < NTILES; ++it) {
        const int cur = it & 1;
        const bool more = (it + 1) < NTILES;

        // ---- prefetch next iter: B-DMA + A float loads (issued first) ----
        if (more) {
            const bf16* bs = bsrc + (size_t)(it + 1) * TILE_ELEMS;
            char* bd = (char*)&Bs[cur ^ 1][0] + wave * 5 * 1024;
            #pragma unroll
            for (int j = 0; j < 5; ++j) {
                __builtin_amdgcn_global_load_lds(
                    (const GLOBAL_AS void*)(bs + j * 512),
                    (LDS_AS void*)(bd + j * 1024), 16, 0, 0);
            }
            const int kn = (it + 1) * 32;
            if (kn + q * 8 < KREAL) {   // zero-guard (last tile, q>=2 only)
                #pragma unroll
                for (int mt = 0; mt < 4; ++mt) {
                    const float* p = ar + (size_t)(mt * 16) * KREAL + kn;
                    fa[mt] = *(const float4*)p;
                    fb[mt] = *(const float4*)(p + 4);
                }
            } else {
                #pragma unroll
                for (int mt = 0; mt < 4; ++mt)
                    fa[mt] = fb[mt] = (float4){0.f, 0.f, 0.f, 0.f};
            }
        }

        // ---- MFMA: 8 B-frags (this wave's col-half), each feeds 4 MFMAs ----
        #pragma unroll
        for (int nt = 0; nt < 8; ++nt) {
            bf16x8 b = *(const bf16x8*)&Bs[cur][((nh * 8 + nt) * 16 + c) * TROW + q * 8];
            #pragma unroll
            for (int mt = 0; mt < 4; ++mt)
                acc[mt][nt] = __builtin_amdgcn_mfma_f32_16x16x32_bf16(
                    a[mt], b, acc[mt][nt], 0, 0, 0);
        }

        // ---- convert prefetched A (waits on A loads AFTER compute) ----
        if (more) {
            #pragma unroll
            for (int mt = 0; mt < 4; ++mt) a[mt] = cvt8(fa[mt], fb[mt]);
        }

        __syncthreads();   // next tile resident; old buffer reads done
    }

    // ---- epilogue: h = relu(acc + b1); out = h @ w2 + b2 ----
    // C/D layout: col = lane&15 (= n within tile), row = q*4 + reg
    float bl[8];
    #pragma unroll
    for (int nt = 0; nt < 8; ++nt) bl[nt] = b1s[nh * 128 + nt * 16 + c];

    #pragma unroll
    for (int mt = 0; mt < 4; ++mt)
        #pragma unroll
        for (int nt = 0; nt < 8; ++nt)
            #pragma unroll
            for (int r = 0; r < 4; ++r) {
                float v = acc[mt][nt][r] + bl[nt];
                acc[mt][nt][r] = v > 0.f ? v : 0.f;
            }

    // Partial 256->10: this wave's 128-col half. After the 4 DPP adds the sum
    // is uniform across the 16 c-lanes; lane c keeps the j==c value.
    float keep[4][4];
    #pragma unroll
    for (int mt = 0; mt < 4; ++mt)
        #pragma unroll
        for (int r = 0; r < 4; ++r) keep[mt][r] = 0.f;

    #pragma unroll 1
    for (int j = 0; j < 10; ++j) {
        float wj[8];
        #pragma unroll
        for (int nt = 0; nt < 8; ++nt) wj[nt] = w2s[nh * 128 + nt * 16 + c][j];
        #pragma unroll
        for (int mt = 0; mt < 4; ++mt)
            #pragma unroll
            for (int r = 0; r < 4; ++r) {
                float s = 0.f;
                #pragma unroll
                for (int nt = 0; nt < 8; ++nt) s += acc[mt][nt][r] * wj[nt];
                s = dpp_add<0xB1>(s);    // lane ^ 1
                s = dpp_add<0x4E>(s);    // lane ^ 2
                s = dpp_add<0x124>(s);   // row_ror:4 (quad-sums uniform)
                s = dpp_add<0x128>(s);   // row_ror:8
                if (c == j) keep[mt][r] = s;
            }
    }

    // Cross-wave combine: odd col-half publishes partials in the dead Bs
    // buffer (last loop barrier guarantees all Bs reads are done).
    float* part = (float*)&Bs[0][0];   // 2*4*4*4*16 floats = 2 KB
    if (nh == 1) {
        #pragma unroll
        for (int mt = 0; mt < 4; ++mt)
            #pragma unroll
            for (int r = 0; r < 4; ++r)
                if (c < 10)
                    part[((((pair * 4 + mt) * 4 + r) * 4 + q) << 4) + c] = keep[mt][r];
    }
    __syncthreads();
    if (nh == 0) {
        #pragma unroll
        for (int mt = 0; mt < 4; ++mt)
            #pragma unroll
            for (int r = 0; r < 4; ++r)
                if (c < 10) {
                    const int row = row0 + pair * 64 + mt * 16 + q * 4 + r;
                    out[(size_t)row * 10 + c] =
                        keep[mt][r] +
                        part[((((pair * 4 + mt) * 4 + r) * 4 + q) << 4) + c] +
                        b2s[c];
                }
    }
}

extern "C" void kernel_launch(void* const* d_in, const int* in_sizes, int n_in,
                              void* d_out, int out_size, void* d_ws, size_t ws_size,
                              hipStream_t stream) {
    const float* x  = (const float*)d_in[0];
    const float* wc = (const float*)d_in[1];
    const float* w1 = (const float*)d_in[2];
    const float* b1 = (const float*)d_in[3];
    const float* w2 = (const float*)d_in[4];
    const float* b2 = (const float*)d_in[5];
    float* out = (float*)d_out;
    bf16* W = (bf16*)d_ws;  // 25 * 10240 * 2 B = 500 KB scratch

    prep_w1tt<<<dim3(NTILES * TROW), dim3(256), 0, stream>>>(wc, w1, W);
    fused_mlp<<<dim3(65536 / 128), dim3(256), 0, stream>>>(x, W, b1, w2, b2, out);
}